// Round 15
// baseline (36.166 us; speedup 1.0000x reference)
//
#include <hip/hip_runtime.h>

#define NCLS 100
#define NROWS 262144
#define MAIN_BLOCKS 2048
#define MAIN_THREADS 256
#define NWAVES (MAIN_THREADS / 64)
#define TILE_ROWS 32
#define NTILES 4                                  // rows/block = 128
#define TILE_F4 (TILE_ROWS * 25)                  // 800 float4 per tile
#define PART_LD MAIN_BLOCKS                       // transposed: part[c*2048 + b]
#define NPC (2 * NCLS + 1)                        // 201 partial columns
#define WS_NEEDED ((size_t)NPC * PART_LD * 4)

// Lessons banked:
//  R8:  ticket atomic whose RETURN gates completion -> ~300us serial. Never.
//  R9:  coop launch not graph-capturable; launch_bounds(...,8) -> spill.
//  R10: non-temporal loads regressed (two-touch lines).
//  R11/R12: pipeline depth + prologue order neutral.
//  R13: runtime select over reg arrays -> scratch demotion. Explicit unroll only.
//  R15: rows are 400B (16B-aligned) -> wave loads = 8 straddling 128B
//       segments at ~4.7TB/s vs 7.1TB/s aligned fill. Stage tiles into LDS
//       with flat aligned copies; read rows from LDS; vtx from LDS.

// ---- per-row softmax + accumulation (identical math to R14 best) ----------
// logw[t][j] = min(logc_j - logc_t, 0); vt = x[row][t] (w[t][t]=1).
#define COMPROW(buf, LGT, VTX, TT) do {                                        \
    float4 e[4];                                                               \
    float sp = 0.f;                                                            \
    _Pragma("unroll")                                                          \
    for (int m = 0; m < 4; ++m) {                                              \
        if (8 * m + k < 25) {                                                  \
            e[m].x = __expf(buf[m].x + fminf(lgn[m].x - (LGT), 0.f));          \
            e[m].y = __expf(buf[m].y + fminf(lgn[m].y - (LGT), 0.f));          \
            e[m].z = __expf(buf[m].z + fminf(lgn[m].z - (LGT), 0.f));          \
            e[m].w = __expf(buf[m].w + fminf(lgn[m].w - (LGT), 0.f));          \
            sp += (e[m].x + e[m].y) + (e[m].z + e[m].w);                       \
        } else {                                                               \
            e[m] = make_float4(0.f, 0.f, 0.f, 0.f);                            \
        }                                                                      \
    }                                                                          \
    float s = sp + __shfl_xor(sp, 1, 64);                                      \
    s += __shfl_xor(s, 2, 64);                                                 \
    s += __shfl_xor(s, 4, 64);                                                 \
    const float inv_s = 1.0f / s;                                              \
    if (k == 0) {                                                              \
        loss_local += __logf(s) - (VTX);                                       \
        const float pt = __expf(VTX) * inv_s;                                  \
        atomicAdd(&lds_q[TT], pt);                                             \
        atomicAdd(&lds_pos[TT], 1.0f - pt);                                    \
    }                                                                          \
    _Pragma("unroll")                                                          \
    for (int m = 0; m < 4; ++m) {                                              \
        if (8 * m + k < 25) {                                                  \
            S4[m].x = fmaf(e[m].x, inv_s, S4[m].x);                            \
            S4[m].y = fmaf(e[m].y, inv_s, S4[m].y);                            \
            S4[m].z = fmaf(e[m].z, inv_s, S4[m].z);                            \
            S4[m].w = fmaf(e[m].w, inv_s, S4[m].w);                            \
        }                                                                      \
    }                                                                          \
} while (0)

// stage tile TI: flat, aligned, fully-coalesced float4 copy (800 f4 = 12.8KB)
#define STAGE(TI) do {                                                         \
    _Pragma("unroll")                                                          \
    for (int i_ = 0; i_ < 4; ++i_) {                                           \
        const int idx_ = i_ * MAIN_THREADS + threadIdx.x;                      \
        if (idx_ < TILE_F4)                                                    \
            lds_x4[idx_] = x4[base_f4 + (TI) * TILE_F4 + idx_];                \
    }                                                                          \
} while (0)

// compute tile TI: octet reads its row from LDS (b128, 2-way aliasing = free)
#define COMPTILE(TI) do {                                                      \
    const int t_ = tr[TI];                                                     \
    const float lgt_ = lgt[TI];                                                \
    float4 buf[4];                                                             \
    buf[0] = lds_x4[oct * 25 + k];                                             \
    buf[1] = lds_x4[oct * 25 + 8 + k];                                         \
    buf[2] = lds_x4[oct * 25 + 16 + k];                                        \
    buf[3] = (k == 0) ? lds_x4[oct * 25 + 24]                                  \
                      : make_float4(0.f, 0.f, 0.f, 0.f);                       \
    const float vt_ = lds_xs[oct * NCLS + t_];   /* octet-uniform: broadcast */\
    COMPROW(buf, lgt_, vt_, t_);                                               \
} while (0)

// ---------------------------------------------------------------------------
// main: block owns 128 contiguous rows = 4 tiles x 32 rows. Per tile:
// aligned flat stage -> barrier -> 1 row/octet from LDS -> barrier.
// Epilogue: wave butterflies -> LDS -> transposed per-block partials (or
// global atomics fallback when ws is too small).
// ---------------------------------------------------------------------------
__global__ __launch_bounds__(MAIN_THREADS, 4)
void seesaw_main(const float* __restrict__ x,
                 const int* __restrict__ target,
                 const float* __restrict__ wm,
                 float* __restrict__ part,
                 float* __restrict__ out,
                 int use_part) {
    __shared__ float4 lds_x4[TILE_F4];       // 12.8KB row tile
    __shared__ float lds_lgn[NCLS];          // logc_j = log(wm[0][j])
    __shared__ float lds_q[NCLS];            // sum of p_t per class
    __shared__ float lds_pos[NCLS];          // sum of (1 - p_t) per class
    __shared__ float lds_S[NWAVES][NCLS];    // per-wave reduced column sums
    __shared__ float lds_loss[NWAVES];

    const int lane = threadIdx.x & 63;
    const int wave = threadIdx.x >> 6;
    const int k    = threadIdx.x & 7;                 // slot within octet
    const int oct  = threadIdx.x >> 3;                // local octet = local row
    const float* lds_xs = reinterpret_cast<const float*>(lds_x4);
    const float4* x4 = reinterpret_cast<const float4*>(x);
    const size_t base_f4 = (size_t)blockIdx.x * (NTILES * TILE_F4);
    const int row0 = blockIdx.x * (NTILES * TILE_ROWS) + oct;

    // prologue: targets (coalesced, dedup'd), log-consts, zero accumulators
    int tr[NTILES];
    tr[0] = target[row0];
    tr[1] = target[row0 + TILE_ROWS];
    tr[2] = target[row0 + 2 * TILE_ROWS];
    tr[3] = target[row0 + 3 * TILE_ROWS];

    if (threadIdx.x < NCLS) {
        lds_lgn[threadIdx.x] = __logf(wm[threadIdx.x]);   // row 0 of wm
        lds_q[threadIdx.x] = 0.f;
        lds_pos[threadIdx.x] = 0.f;
    }
    STAGE(0);
    __syncthreads();

    // lane's 16 class log-constants -> registers
    float4 lgn[4];
#pragma unroll
    for (int m = 0; m < 4; ++m) {
        const int g = 8 * m + k;
        if (g < 25) {
            lgn[m].x = lds_lgn[4 * g + 0];
            lgn[m].y = lds_lgn[4 * g + 1];
            lgn[m].z = lds_lgn[4 * g + 2];
            lgn[m].w = lds_lgn[4 * g + 3];
        } else {
            lgn[m] = make_float4(0.f, 0.f, 0.f, 0.f);
        }
    }
    float lgt[NTILES];
    lgt[0] = lds_lgn[tr[0]];
    lgt[1] = lds_lgn[tr[1]];
    lgt[2] = lds_lgn[tr[2]];
    lgt[3] = lds_lgn[tr[3]];

    float4 S4[4];
#pragma unroll
    for (int m = 0; m < 4; ++m) S4[m] = make_float4(0.f, 0.f, 0.f, 0.f);
    float loss_local = 0.0f;

    // tile sequence (explicit unroll — no runtime-indexed register arrays)
    COMPTILE(0);
    __syncthreads();          // everyone done reading tile 0
    STAGE(1);
    __syncthreads();          // tile 1 ready
    COMPTILE(1);
    __syncthreads();
    STAGE(2);
    __syncthreads();
    COMPTILE(2);
    __syncthreads();
    STAGE(3);
    __syncthreads();
    COMPTILE(3);

    // ---- reduce S across the wave's 8 octets (masks preserve k = lane&7) ----
#pragma unroll
    for (int m = 0; m < 4; ++m) {
#pragma unroll
        for (int msk = 8; msk <= 32; msk <<= 1) {
            S4[m].x += __shfl_xor(S4[m].x, msk, 64);
            S4[m].y += __shfl_xor(S4[m].y, msk, 64);
            S4[m].z += __shfl_xor(S4[m].z, msk, 64);
            S4[m].w += __shfl_xor(S4[m].w, msk, 64);
        }
    }
#pragma unroll
    for (int msk = 1; msk < 64; msk <<= 1)
        loss_local += __shfl_xor(loss_local, msk, 64);
    if (lane == 0) lds_loss[wave] = loss_local;

    if (lane < 8) {                       // lane == its k slot; holds wave sums
#pragma unroll
        for (int m = 0; m < 4; ++m) {
            const int g = 8 * m + lane;
            if (g < 25) {
                lds_S[wave][4 * g + 0] = S4[m].x;
                lds_S[wave][4 * g + 1] = S4[m].y;
                lds_S[wave][4 * g + 2] = S4[m].z;
                lds_S[wave][4 * g + 3] = S4[m].w;
            }
        }
    }
    __syncthreads();

    if (use_part) {
        // transposed partials: column j contiguous over blocks -> coalesced tail
        if (threadIdx.x < NCLS) {
            const int j = threadIdx.x;
            float sb = 0.f;
#pragma unroll
            for (int w = 0; w < NWAVES; ++w) sb += lds_S[w][j];
            part[(size_t)j * PART_LD + blockIdx.x] = sb - lds_q[j];          // neg
            part[(size_t)(NCLS + j) * PART_LD + blockIdx.x] = lds_pos[j];    // pos
        }
        if (threadIdx.x == 0) {
            float l = 0.f;
#pragma unroll
            for (int w = 0; w < NWAVES; ++w) l += lds_loss[w];
            part[(size_t)(2 * NCLS) * PART_LD + blockIdx.x] = l;             // loss
        }
    } else {
        if (threadIdx.x < NCLS) {
            const int j = threadIdx.x;
            float sb = 0.f;
#pragma unroll
            for (int w = 0; w < NWAVES; ++w) sb += lds_S[w][j];
            atomicAdd(&out[1 + j], sb - lds_q[j]);
            atomicAdd(&out[1 + NCLS + j], lds_pos[j]);
        }
        if (threadIdx.x == 0) {
            float l = 0.f;
#pragma unroll
            for (int w = 0; w < NWAVES; ++w) l += lds_loss[w];
            atomicAdd(&out[0], l);
        }
    }
}

// ---------------------------------------------------------------------------
// tail (partials path): block c<100 reduces neg & pos columns (coalesced 8KB
// runs) and writes neg, pos, ratio; block c==100 reduces loss and divides by B.
// ---------------------------------------------------------------------------
__global__ void seesaw_tail(const float* __restrict__ part,
                            const float* __restrict__ neg_in,
                            const float* __restrict__ pos_in,
                            float* __restrict__ out) {
    const int c = blockIdx.x;                 // 0..100
    __shared__ float redn[NWAVES], redp[NWAVES];
    const int lane = threadIdx.x & 63;
    const int wave = threadIdx.x >> 6;

    float sn = 0.f, sp = 0.f;
    if (c < NCLS) {
        for (int b = threadIdx.x; b < PART_LD; b += MAIN_THREADS) {
            sn += part[(size_t)c * PART_LD + b];
            sp += part[(size_t)(NCLS + c) * PART_LD + b];
        }
    } else {
        for (int b = threadIdx.x; b < PART_LD; b += MAIN_THREADS)
            sn += part[(size_t)(2 * NCLS) * PART_LD + b];
    }
#pragma unroll
    for (int msk = 1; msk < 64; msk <<= 1) {
        sn += __shfl_xor(sn, msk, 64);
        sp += __shfl_xor(sp, msk, 64);
    }
    if (lane == 0) { redn[wave] = sn; redp[wave] = sp; }
    __syncthreads();
    if (threadIdx.x == 0) {
        float tn = 0.f, tp = 0.f;
#pragma unroll
        for (int w = 0; w < NWAVES; ++w) { tn += redn[w]; tp += redp[w]; }
        if (c < NCLS) {
            const float neg = neg_in[c] + tn;
            const float pos = pos_in[c] + tp;
            out[1 + c] = neg;
            out[1 + NCLS + c] = pos;
            out[1 + 2 * NCLS + c] = pos / neg;
        } else {
            out[0] = tn * (1.0f / (float)NROWS);
        }
    }
}

// ---------------------------------------------------------------------------
// fallback path (ws too small): init accumulators / finalize after atomics
// ---------------------------------------------------------------------------
__global__ void seesaw_init(const float* __restrict__ neg_in,
                            const float* __restrict__ pos_in,
                            float* __restrict__ out) {
    int i = threadIdx.x;
    if (i == 0) out[0] = 0.0f;
    if (i < NCLS) {
        out[1 + i] = neg_in[i];
        out[1 + NCLS + i] = pos_in[i];
    }
}

__global__ void seesaw_fin(float* __restrict__ out) {
    int j = threadIdx.x;
    if (j == 0) out[0] *= (1.0f / (float)NROWS);
    if (j < NCLS) out[1 + 2 * NCLS + j] = out[1 + NCLS + j] / out[1 + j];
}

extern "C" void kernel_launch(void* const* d_in, const int* in_sizes, int n_in,
                              void* d_out, int out_size, void* d_ws, size_t ws_size,
                              hipStream_t stream) {
    const float* x      = (const float*)d_in[0];
    const int*   target = (const int*)d_in[1];
    const float* wm     = (const float*)d_in[2];
    const float* neg_in = (const float*)d_in[3];
    const float* pos_in = (const float*)d_in[4];
    float* out  = (float*)d_out;
    float* part = (float*)d_ws;

    if (ws_size >= WS_NEEDED) {
        hipLaunchKernelGGL(seesaw_main, dim3(MAIN_BLOCKS), dim3(MAIN_THREADS), 0, stream,
                           x, target, wm, part, out, 1);
        hipLaunchKernelGGL(seesaw_tail, dim3(NCLS + 1), dim3(MAIN_THREADS), 0, stream,
                           part, neg_in, pos_in, out);
    } else {
        hipLaunchKernelGGL(seesaw_init, dim3(1), dim3(256), 0, stream,
                           neg_in, pos_in, out);
        hipLaunchKernelGGL(seesaw_main, dim3(MAIN_BLOCKS), dim3(MAIN_THREADS), 0, stream,
                           x, target, wm, part, out, 0);
        hipLaunchKernelGGL(seesaw_fin, dim3(1), dim3(128), 0, stream, out);
    }
}

// Round 16
// 33.171 us; speedup vs baseline: 1.0903x; 1.0903x over previous
//
#include <hip/hip_runtime.h>

#define NCLS 100
#define NROWS 262144
#define MAIN_BLOCKS 2048
#define MAIN_THREADS 256
#define NWAVES (MAIN_THREADS / 64)
#define TILE_ROWS 32
#define NTILES 4                                  // rows/block = 128
#define TILE_F4 (TILE_ROWS * 25)                  // 800 float4 per tile
#define PART_LD MAIN_BLOCKS                       // transposed: part[c*2048 + b]
#define NPC (2 * NCLS + 1)                        // 201 partial columns
#define WS_NEEDED ((size_t)NPC * PART_LD * 4)

// Lessons banked:
//  R8:  return-gated ticket atomic -> ~300us serial. Never.
//  R9:  coop launch not graph-capturable; launch_bounds(...,8) -> spill.
//  R10: non-temporal loads regressed (two-touch lines).
//  R11/R12: pipeline depth + prologue order neutral.
//  R13: runtime select over reg arrays -> scratch demotion. Explicit unroll only.
//  R15: SERIAL LDS staging (2 barriers/tile, no stage/compute overlap)
//       regressed 4us. This round: async global_load_lds double-buffer,
//       1 barrier/tile, stage(i+1) in flight under compute(i).

// ---- per-row softmax + accumulation (identical math to R14 best) ----------
#define COMPROW(buf, LGT, VTX, TT) do {                                        \
    float4 e[4];                                                               \
    float sp = 0.f;                                                            \
    _Pragma("unroll")                                                          \
    for (int m = 0; m < 4; ++m) {                                              \
        if (8 * m + k < 25) {                                                  \
            e[m].x = __expf(buf[m].x + fminf(lgn[m].x - (LGT), 0.f));          \
            e[m].y = __expf(buf[m].y + fminf(lgn[m].y - (LGT), 0.f));          \
            e[m].z = __expf(buf[m].z + fminf(lgn[m].z - (LGT), 0.f));          \
            e[m].w = __expf(buf[m].w + fminf(lgn[m].w - (LGT), 0.f));          \
            sp += (e[m].x + e[m].y) + (e[m].z + e[m].w);                       \
        } else {                                                               \
            e[m] = make_float4(0.f, 0.f, 0.f, 0.f);                            \
        }                                                                      \
    }                                                                          \
    float s = sp + __shfl_xor(sp, 1, 64);                                      \
    s += __shfl_xor(s, 2, 64);                                                 \
    s += __shfl_xor(s, 4, 64);                                                 \
    const float inv_s = 1.0f / s;                                              \
    if (k == 0) {                                                              \
        loss_local += __logf(s) - (VTX);                                       \
        const float pt = __expf(VTX) * inv_s;                                  \
        atomicAdd(&lds_q[TT], pt);                                             \
        atomicAdd(&lds_pos[TT], 1.0f - pt);                                    \
    }                                                                          \
    _Pragma("unroll")                                                          \
    for (int m = 0; m < 4; ++m) {                                              \
        if (8 * m + k < 25) {                                                  \
            S4[m].x = fmaf(e[m].x, inv_s, S4[m].x);                            \
            S4[m].y = fmaf(e[m].y, inv_s, S4[m].y);                            \
            S4[m].z = fmaf(e[m].z, inv_s, S4[m].z);                            \
            S4[m].w = fmaf(e[m].w, inv_s, S4[m].w);                            \
        }                                                                      \
    }                                                                          \
} while (0)

// async stage tile TI into DSTBUF via global_load_lds (width 16, linear dest:
// idx = i*256 + tid is lane-contiguous per wave -> wave-uniform base + lane*16)
#define STAGE_GL(DSTBUF, TI) do {                                              \
    _Pragma("unroll")                                                          \
    for (int i_ = 0; i_ < 4; ++i_) {                                           \
        const int idx_ = i_ * MAIN_THREADS + threadIdx.x;                      \
        if (idx_ < TILE_F4) {                                                  \
            __builtin_amdgcn_global_load_lds(                                  \
                (const __attribute__((address_space(1))) void*)                \
                    &x4[base_f4 + (size_t)(TI) * TILE_F4 + idx_],              \
                (__attribute__((address_space(3))) void*)&DSTBUF[idx_],        \
                16, 0, 0);                                                     \
        }                                                                      \
    }                                                                          \
} while (0)

// compute tile TI from SRCBUF: octet reads its row (b128); vt scalar broadcast
#define COMPTILE(SRCBUF, TI) do {                                              \
    const int t_ = tr[TI];                                                     \
    const float lgt_ = lgt[TI];                                                \
    float4 buf[4];                                                             \
    buf[0] = SRCBUF[oct * 25 + k];                                             \
    buf[1] = SRCBUF[oct * 25 + 8 + k];                                         \
    buf[2] = SRCBUF[oct * 25 + 16 + k];                                        \
    buf[3] = (k == 0) ? SRCBUF[oct * 25 + 24]                                  \
                      : make_float4(0.f, 0.f, 0.f, 0.f);                       \
    const float vt_ =                                                          \
        reinterpret_cast<const float*>(SRCBUF)[oct * NCLS + t_];               \
    COMPROW(buf, lgt_, vt_, t_);                                               \
} while (0)

// ---------------------------------------------------------------------------
// main: block owns 128 contiguous rows = 4 tiles x 32 rows, double-buffered:
//   STAGE(A,0); sync; STAGE(B,1); COMP(A,0); sync; STAGE(A,2); COMP(B,1); ...
// One barrier per tile; staging loads fly under compute (vmcnt drained at the
// barrier). Epilogue: wave butterflies -> LDS -> transposed per-block partials.
// ---------------------------------------------------------------------------
__global__ __launch_bounds__(MAIN_THREADS, 4)
void seesaw_main(const float* __restrict__ x,
                 const int* __restrict__ target,
                 const float* __restrict__ wm,
                 float* __restrict__ part,
                 float* __restrict__ out,
                 int use_part) {
    __shared__ float4 lds_bufA[TILE_F4];     // 12.8KB tile buffer A
    __shared__ float4 lds_bufB[TILE_F4];     // 12.8KB tile buffer B
    __shared__ float lds_lgn[NCLS];          // logc_j = log(wm[0][j])
    __shared__ float lds_q[NCLS];            // sum of p_t per class
    __shared__ float lds_pos[NCLS];          // sum of (1 - p_t) per class
    __shared__ float lds_S[NWAVES][NCLS];    // per-wave reduced column sums
    __shared__ float lds_loss[NWAVES];

    const int lane = threadIdx.x & 63;
    const int wave = threadIdx.x >> 6;
    const int k    = threadIdx.x & 7;                 // slot within octet
    const int oct  = threadIdx.x >> 3;                // local octet = local row
    const float4* x4 = reinterpret_cast<const float4*>(x);
    const size_t base_f4 = (size_t)blockIdx.x * (NTILES * TILE_F4);
    const int row0 = blockIdx.x * (NTILES * TILE_ROWS) + oct;

    // issue tile-0 staging FIRST (flies under the whole prologue)
    STAGE_GL(lds_bufA, 0);

    // prologue: targets (coalesced), log-consts, zero accumulators
    int tr[NTILES];
    tr[0] = target[row0];
    tr[1] = target[row0 + TILE_ROWS];
    tr[2] = target[row0 + 2 * TILE_ROWS];
    tr[3] = target[row0 + 3 * TILE_ROWS];

    if (threadIdx.x < NCLS) {
        lds_lgn[threadIdx.x] = __logf(wm[threadIdx.x]);   // row 0 of wm
        lds_q[threadIdx.x] = 0.f;
        lds_pos[threadIdx.x] = 0.f;
    }
    __syncthreads();                          // tile 0 + lgn ready

    float4 lgn[4];
#pragma unroll
    for (int m = 0; m < 4; ++m) {
        const int g = 8 * m + k;
        if (g < 25) {
            lgn[m].x = lds_lgn[4 * g + 0];
            lgn[m].y = lds_lgn[4 * g + 1];
            lgn[m].z = lds_lgn[4 * g + 2];
            lgn[m].w = lds_lgn[4 * g + 3];
        } else {
            lgn[m] = make_float4(0.f, 0.f, 0.f, 0.f);
        }
    }
    float lgt[NTILES];
    lgt[0] = lds_lgn[tr[0]];
    lgt[1] = lds_lgn[tr[1]];
    lgt[2] = lds_lgn[tr[2]];
    lgt[3] = lds_lgn[tr[3]];

    float4 S4[4];
#pragma unroll
    for (int m = 0; m < 4; ++m) S4[m] = make_float4(0.f, 0.f, 0.f, 0.f);
    float loss_local = 0.0f;

    // double-buffered tile pipeline (explicit unroll, named buffers)
    STAGE_GL(lds_bufB, 1);                    // async: flies under compute
    COMPTILE(lds_bufA, 0);
    __syncthreads();                          // B ready, A free
    STAGE_GL(lds_bufA, 2);
    COMPTILE(lds_bufB, 1);
    __syncthreads();                          // A ready, B free
    STAGE_GL(lds_bufB, 3);
    COMPTILE(lds_bufA, 2);
    __syncthreads();                          // B ready
    COMPTILE(lds_bufB, 3);

    // ---- reduce S across the wave's 8 octets (masks preserve k = lane&7) ----
#pragma unroll
    for (int m = 0; m < 4; ++m) {
#pragma unroll
        for (int msk = 8; msk <= 32; msk <<= 1) {
            S4[m].x += __shfl_xor(S4[m].x, msk, 64);
            S4[m].y += __shfl_xor(S4[m].y, msk, 64);
            S4[m].z += __shfl_xor(S4[m].z, msk, 64);
            S4[m].w += __shfl_xor(S4[m].w, msk, 64);
        }
    }
#pragma unroll
    for (int msk = 1; msk < 64; msk <<= 1)
        loss_local += __shfl_xor(loss_local, msk, 64);
    if (lane == 0) lds_loss[wave] = loss_local;

    if (lane < 8) {                       // lane == its k slot; holds wave sums
#pragma unroll
        for (int m = 0; m < 4; ++m) {
            const int g = 8 * m + lane;
            if (g < 25) {
                lds_S[wave][4 * g + 0] = S4[m].x;
                lds_S[wave][4 * g + 1] = S4[m].y;
                lds_S[wave][4 * g + 2] = S4[m].z;
                lds_S[wave][4 * g + 3] = S4[m].w;
            }
        }
    }
    __syncthreads();

    if (use_part) {
        // transposed partials: column j contiguous over blocks -> coalesced tail
        if (threadIdx.x < NCLS) {
            const int j = threadIdx.x;
            float sb = 0.f;
#pragma unroll
            for (int w = 0; w < NWAVES; ++w) sb += lds_S[w][j];
            part[(size_t)j * PART_LD + blockIdx.x] = sb - lds_q[j];          // neg
            part[(size_t)(NCLS + j) * PART_LD + blockIdx.x] = lds_pos[j];    // pos
        }
        if (threadIdx.x == 0) {
            float l = 0.f;
#pragma unroll
            for (int w = 0; w < NWAVES; ++w) l += lds_loss[w];
            part[(size_t)(2 * NCLS) * PART_LD + blockIdx.x] = l;             // loss
        }
    } else {
        if (threadIdx.x < NCLS) {
            const int j = threadIdx.x;
            float sb = 0.f;
#pragma unroll
            for (int w = 0; w < NWAVES; ++w) sb += lds_S[w][j];
            atomicAdd(&out[1 + j], sb - lds_q[j]);
            atomicAdd(&out[1 + NCLS + j], lds_pos[j]);
        }
        if (threadIdx.x == 0) {
            float l = 0.f;
#pragma unroll
            for (int w = 0; w < NWAVES; ++w) l += lds_loss[w];
            atomicAdd(&out[0], l);
        }
    }
}

// ---------------------------------------------------------------------------
// tail (partials path): block c<100 reduces neg & pos columns (coalesced 8KB
// runs) and writes neg, pos, ratio; block c==100 reduces loss and divides by B.
// ---------------------------------------------------------------------------
__global__ void seesaw_tail(const float* __restrict__ part,
                            const float* __restrict__ neg_in,
                            const float* __restrict__ pos_in,
                            float* __restrict__ out) {
    const int c = blockIdx.x;                 // 0..100
    __shared__ float redn[NWAVES], redp[NWAVES];
    const int lane = threadIdx.x & 63;
    const int wave = threadIdx.x >> 6;

    float sn = 0.f, sp = 0.f;
    if (c < NCLS) {
        for (int b = threadIdx.x; b < PART_LD; b += MAIN_THREADS) {
            sn += part[(size_t)c * PART_LD + b];
            sp += part[(size_t)(NCLS + c) * PART_LD + b];
        }
    } else {
        for (int b = threadIdx.x; b < PART_LD; b += MAIN_THREADS)
            sn += part[(size_t)(2 * NCLS) * PART_LD + b];
    }
#pragma unroll
    for (int msk = 1; msk < 64; msk <<= 1) {
        sn += __shfl_xor(sn, msk, 64);
        sp += __shfl_xor(sp, msk, 64);
    }
    if (lane == 0) { redn[wave] = sn; redp[wave] = sp; }
    __syncthreads();
    if (threadIdx.x == 0) {
        float tn = 0.f, tp = 0.f;
#pragma unroll
        for (int w = 0; w < NWAVES; ++w) { tn += redn[w]; tp += redp[w]; }
        if (c < NCLS) {
            const float neg = neg_in[c] + tn;
            const float pos = pos_in[c] + tp;
            out[1 + c] = neg;
            out[1 + NCLS + c] = pos;
            out[1 + 2 * NCLS + c] = pos / neg;
        } else {
            out[0] = tn * (1.0f / (float)NROWS);
        }
    }
}

// ---------------------------------------------------------------------------
// fallback path (ws too small): init accumulators / finalize after atomics
// ---------------------------------------------------------------------------
__global__ void seesaw_init(const float* __restrict__ neg_in,
                            const float* __restrict__ pos_in,
                            float* __restrict__ out) {
    int i = threadIdx.x;
    if (i == 0) out[0] = 0.0f;
    if (i < NCLS) {
        out[1 + i] = neg_in[i];
        out[1 + NCLS + i] = pos_in[i];
    }
}

__global__ void seesaw_fin(float* __restrict__ out) {
    int j = threadIdx.x;
    if (j == 0) out[0] *= (1.0f / (float)NROWS);
    if (j < NCLS) out[1 + 2 * NCLS + j] = out[1 + NCLS + j] / out[1 + j];
}

extern "C" void kernel_launch(void* const* d_in, const int* in_sizes, int n_in,
                              void* d_out, int out_size, void* d_ws, size_t ws_size,
                              hipStream_t stream) {
    const float* x      = (const float*)d_in[0];
    const int*   target = (const int*)d_in[1];
    const float* wm     = (const float*)d_in[2];
    const float* neg_in = (const float*)d_in[3];
    const float* pos_in = (const float*)d_in[4];
    float* out  = (float*)d_out;
    float* part = (float*)d_ws;

    if (ws_size >= WS_NEEDED) {
        hipLaunchKernelGGL(seesaw_main, dim3(MAIN_BLOCKS), dim3(MAIN_THREADS), 0, stream,
                           x, target, wm, part, out, 1);
        hipLaunchKernelGGL(seesaw_tail, dim3(NCLS + 1), dim3(MAIN_THREADS), 0, stream,
                           part, neg_in, pos_in, out);
    } else {
        hipLaunchKernelGGL(seesaw_init, dim3(1), dim3(256), 0, stream,
                           neg_in, pos_in, out);
        hipLaunchKernelGGL(seesaw_main, dim3(MAIN_BLOCKS), dim3(MAIN_THREADS), 0, stream,
                           x, target, wm, part, out, 0);
        hipLaunchKernelGGL(seesaw_fin, dim3(1), dim3(128), 0, stream, out);
    }
}

// Round 17
// 31.813 us; speedup vs baseline: 1.1368x; 1.0427x over previous
//
#include <hip/hip_runtime.h>

#define NCLS 100
#define NROWS 262144
#define MAIN_BLOCKS 2048
#define MAIN_THREADS 256
#define NWAVES (MAIN_THREADS / 64)
#define NOCT ((MAIN_BLOCKS * MAIN_THREADS) / 8)   // 65536 octets, 4 rows each
#define ROWS_PER_OCT (NROWS / NOCT)               // 4
#define PART_LD MAIN_BLOCKS                       // transposed: part[c*2048 + b]
#define NPC (2 * NCLS + 1)                        // 201 partial columns
#define WS_NEEDED ((size_t)NPC * PART_LD * 4)

// Final ledger (best = this kernel, 31.9us):
//  R8:  return-gated ticket atomic -> ~300us serialized cross-XCD RMWs. Never.
//  R9:  coop launch not graph-capturable; launch_bounds(...,8) -> spill.
//  R10: non-temporal loads -4us (evict-first breaks two-touch lines).
//  R11/R12: pipeline depth, prologue order: neutral.
//  R13: runtime select over reg arrays -> scratch demotion (-33us).
//  R15: serial LDS staging -4us (barrier lockstep kills MLP).
//  R16: async global_load_lds double-buffer -1.3us -> ALIGNMENT THEORY DEAD:
//       aligned staged reads run no faster than strided register streaming.
//  Structure: main ~25us (100MB @ ~4TB/s practical cap for this pattern),
//  tail ~1-2us, 2 graph nodes ~6us. Three independent x-stream designs
//  converge to 32 +/- 1.3us.

// load lane k's slice of one row: groups g = 8m+k, g < 25 (m=3 only for k==0)
#define LOADX(buf, rp) do {                                                    \
    buf[0] = (rp)[k];                                                          \
    buf[1] = (rp)[8 + k];                                                      \
    buf[2] = (rp)[16 + k];                                                     \
    buf[3] = (k == 0) ? (rp)[24] : make_float4(0.f, 0.f, 0.f, 0.f);            \
} while (0)

// per-row softmax + accumulation. logw[t][j] = min(logc_j - logc_t, 0); vt = x[row][t].
#define COMPROW(buf, LGT, VTX, TT) do {                                        \
    float4 e[4];                                                               \
    float sp = 0.f;                                                            \
    _Pragma("unroll")                                                          \
    for (int m = 0; m < 4; ++m) {                                              \
        if (8 * m + k < 25) {                                                  \
            e[m].x = __expf(buf[m].x + fminf(lgn[m].x - (LGT), 0.f));          \
            e[m].y = __expf(buf[m].y + fminf(lgn[m].y - (LGT), 0.f));          \
            e[m].z = __expf(buf[m].z + fminf(lgn[m].z - (LGT), 0.f));          \
            e[m].w = __expf(buf[m].w + fminf(lgn[m].w - (LGT), 0.f));          \
            sp += (e[m].x + e[m].y) + (e[m].z + e[m].w);                       \
        } else {                                                               \
            e[m] = make_float4(0.f, 0.f, 0.f, 0.f);                            \
        }                                                                      \
    }                                                                          \
    float s = sp + __shfl_xor(sp, 1, 64);                                      \
    s += __shfl_xor(s, 2, 64);                                                 \
    s += __shfl_xor(s, 4, 64);                                                 \
    const float inv_s = 1.0f / s;                                              \
    if (k == 0) {                                                              \
        loss_local += __logf(s) - (VTX);                                       \
        const float pt = __expf(VTX) * inv_s;                                  \
        atomicAdd(&lds_q[TT], pt);                                             \
        atomicAdd(&lds_pos[TT], 1.0f - pt);                                    \
    }                                                                          \
    _Pragma("unroll")                                                          \
    for (int m = 0; m < 4; ++m) {                                              \
        if (8 * m + k < 25) {                                                  \
            S4[m].x = fmaf(e[m].x, inv_s, S4[m].x);                            \
            S4[m].y = fmaf(e[m].y, inv_s, S4[m].y);                            \
            S4[m].z = fmaf(e[m].z, inv_s, S4[m].z);                            \
            S4[m].w = fmaf(e[m].w, inv_s, S4[m].w);                            \
        }                                                                      \
    }                                                                          \
} while (0)

// ---------------------------------------------------------------------------
// main: octet (8 lanes) per row, 4 rows per octet, 3-deep row prefetch.
// Weight row synthesized from per-class constants (no logw table).
// Epilogue: wave butterflies -> LDS -> transposed per-block partials (or
// global atomics fallback when ws is too small).
// ---------------------------------------------------------------------------
__global__ __launch_bounds__(MAIN_THREADS, 4)
void seesaw_main(const float* __restrict__ x,
                 const int* __restrict__ target,
                 const float* __restrict__ wm,
                 float* __restrict__ part,
                 float* __restrict__ out,
                 int use_part) {
    __shared__ float lds_lgn[NCLS];          // logc_j = log(wm[0][j])
    __shared__ float lds_q[NCLS];            // sum of p_t per class
    __shared__ float lds_pos[NCLS];          // sum of (1 - p_t) per class
    __shared__ float lds_S[NWAVES][NCLS];    // per-wave reduced column sums
    __shared__ float lds_loss[NWAVES];

    const int lane = threadIdx.x & 63;
    const int wave = threadIdx.x >> 6;
    const int k    = threadIdx.x & 7;                      // slot within octet
    const int oct  = (blockIdx.x * MAIN_THREADS + threadIdx.x) >> 3;

    // issue target loads before the barrier (independent of LDS prologue)
    int tr[ROWS_PER_OCT];
#pragma unroll
    for (int r = 0; r < ROWS_PER_OCT; ++r) tr[r] = target[oct + r * NOCT];

    if (threadIdx.x < NCLS) {
        lds_lgn[threadIdx.x] = __logf(wm[threadIdx.x]);   // row 0 of wm
        lds_q[threadIdx.x] = 0.f;
        lds_pos[threadIdx.x] = 0.f;
    }
    __syncthreads();

    // target logits (w[t][t]=1) — independent scalar gathers, issue early
    float vtx[ROWS_PER_OCT], lgt[ROWS_PER_OCT];
    const float4* xr[ROWS_PER_OCT];
#pragma unroll
    for (int r = 0; r < ROWS_PER_OCT; ++r) {
        const int row = oct + r * NOCT;
        xr[r] = reinterpret_cast<const float4*>(x + (size_t)row * NCLS);
        vtx[r] = x[(size_t)row * NCLS + tr[r]];
    }

    // lane's 16 class log-constants -> registers (one-time LDS read)
    float4 lgn[4];
#pragma unroll
    for (int m = 0; m < 4; ++m) {
        const int g = 8 * m + k;
        if (g < 25) {
            lgn[m].x = lds_lgn[4 * g + 0];
            lgn[m].y = lds_lgn[4 * g + 1];
            lgn[m].z = lds_lgn[4 * g + 2];
            lgn[m].w = lds_lgn[4 * g + 3];
        } else {
            lgn[m] = make_float4(0.f, 0.f, 0.f, 0.f);
        }
    }
#pragma unroll
    for (int r = 0; r < ROWS_PER_OCT; ++r) lgt[r] = lds_lgn[tr[r]];

    float4 S4[4];
#pragma unroll
    for (int m = 0; m < 4; ++m) S4[m] = make_float4(0.f, 0.f, 0.f, 0.f);
    float loss_local = 0.0f;

    // 3-deep row pipeline (all indices compile-time; rows r..r+2 in flight)
    float4 xv0[4], xv1[4], xv2[4];
    LOADX(xv0, xr[0]);
    LOADX(xv1, xr[1]);
    LOADX(xv2, xr[2]);
    COMPROW(xv0, lgt[0], vtx[0], tr[0]);
    LOADX(xv0, xr[3]);
    COMPROW(xv1, lgt[1], vtx[1], tr[1]);
    COMPROW(xv2, lgt[2], vtx[2], tr[2]);
    COMPROW(xv0, lgt[3], vtx[3], tr[3]);

    // ---- reduce S across the wave's 8 octets (masks preserve k = lane&7) ----
#pragma unroll
    for (int m = 0; m < 4; ++m) {
#pragma unroll
        for (int msk = 8; msk <= 32; msk <<= 1) {
            S4[m].x += __shfl_xor(S4[m].x, msk, 64);
            S4[m].y += __shfl_xor(S4[m].y, msk, 64);
            S4[m].z += __shfl_xor(S4[m].z, msk, 64);
            S4[m].w += __shfl_xor(S4[m].w, msk, 64);
        }
    }
#pragma unroll
    for (int msk = 1; msk < 64; msk <<= 1)
        loss_local += __shfl_xor(loss_local, msk, 64);
    if (lane == 0) lds_loss[wave] = loss_local;

    if (lane < 8) {                       // lane == its k slot; holds wave sums
#pragma unroll
        for (int m = 0; m < 4; ++m) {
            const int g = 8 * m + lane;
            if (g < 25) {
                lds_S[wave][4 * g + 0] = S4[m].x;
                lds_S[wave][4 * g + 1] = S4[m].y;
                lds_S[wave][4 * g + 2] = S4[m].z;
                lds_S[wave][4 * g + 3] = S4[m].w;
            }
        }
    }
    __syncthreads();

    if (use_part) {
        // transposed partials: column j contiguous over blocks -> coalesced tail
        if (threadIdx.x < NCLS) {
            const int j = threadIdx.x;
            float sb = 0.f;
#pragma unroll
            for (int w = 0; w < NWAVES; ++w) sb += lds_S[w][j];
            part[(size_t)j * PART_LD + blockIdx.x] = sb - lds_q[j];          // neg
            part[(size_t)(NCLS + j) * PART_LD + blockIdx.x] = lds_pos[j];    // pos
        }
        if (threadIdx.x == 0) {
            float l = 0.f;
#pragma unroll
            for (int w = 0; w < NWAVES; ++w) l += lds_loss[w];
            part[(size_t)(2 * NCLS) * PART_LD + blockIdx.x] = l;             // loss
        }
    } else {
        if (threadIdx.x < NCLS) {
            const int j = threadIdx.x;
            float sb = 0.f;
#pragma unroll
            for (int w = 0; w < NWAVES; ++w) sb += lds_S[w][j];
            atomicAdd(&out[1 + j], sb - lds_q[j]);
            atomicAdd(&out[1 + NCLS + j], lds_pos[j]);
        }
        if (threadIdx.x == 0) {
            float l = 0.f;
#pragma unroll
            for (int w = 0; w < NWAVES; ++w) l += lds_loss[w];
            atomicAdd(&out[0], l);
        }
    }
}

// ---------------------------------------------------------------------------
// tail (partials path): block c<100 reduces neg & pos columns (coalesced 8KB
// runs) and writes neg, pos, ratio; block c==100 reduces loss and divides by B.
// ---------------------------------------------------------------------------
__global__ void seesaw_tail(const float* __restrict__ part,
                            const float* __restrict__ neg_in,
                            const float* __restrict__ pos_in,
                            float* __restrict__ out) {
    const int c = blockIdx.x;                 // 0..100
    __shared__ float redn[NWAVES], redp[NWAVES];
    const int lane = threadIdx.x & 63;
    const int wave = threadIdx.x >> 6;

    float sn = 0.f, sp = 0.f;
    if (c < NCLS) {
        for (int b = threadIdx.x; b < PART_LD; b += MAIN_THREADS) {
            sn += part[(size_t)c * PART_LD + b];
            sp += part[(size_t)(NCLS + c) * PART_LD + b];
        }
    } else {
        for (int b = threadIdx.x; b < PART_LD; b += MAIN_THREADS)
            sn += part[(size_t)(2 * NCLS) * PART_LD + b];
    }
#pragma unroll
    for (int msk = 1; msk < 64; msk <<= 1) {
        sn += __shfl_xor(sn, msk, 64);
        sp += __shfl_xor(sp, msk, 64);
    }
    if (lane == 0) { redn[wave] = sn; redp[wave] = sp; }
    __syncthreads();
    if (threadIdx.x == 0) {
        float tn = 0.f, tp = 0.f;
#pragma unroll
        for (int w = 0; w < NWAVES; ++w) { tn += redn[w]; tp += redp[w]; }
        if (c < NCLS) {
            const float neg = neg_in[c] + tn;
            const float pos = pos_in[c] + tp;
            out[1 + c] = neg;
            out[1 + NCLS + c] = pos;
            out[1 + 2 * NCLS + c] = pos / neg;
        } else {
            out[0] = tn * (1.0f / (float)NROWS);
        }
    }
}

// ---------------------------------------------------------------------------
// fallback path (ws too small): init accumulators / finalize after atomics
// ---------------------------------------------------------------------------
__global__ void seesaw_init(const float* __restrict__ neg_in,
                            const float* __restrict__ pos_in,
                            float* __restrict__ out) {
    int i = threadIdx.x;
    if (i == 0) out[0] = 0.0f;
    if (i < NCLS) {
        out[1 + i] = neg_in[i];
        out[1 + NCLS + i] = pos_in[i];
    }
}

__global__ void seesaw_fin(float* __restrict__ out) {
    int j = threadIdx.x;
    if (j == 0) out[0] *= (1.0f / (float)NROWS);
    if (j < NCLS) out[1 + 2 * NCLS + j] = out[1 + NCLS + j] / out[1 + j];
}

extern "C" void kernel_launch(void* const* d_in, const int* in_sizes, int n_in,
                              void* d_out, int out_size, void* d_ws, size_t ws_size,
                              hipStream_t stream) {
    const float* x      = (const float*)d_in[0];
    const int*   target = (const int*)d_in[1];
    const float* wm     = (const float*)d_in[2];
    const float* neg_in = (const float*)d_in[3];
    const float* pos_in = (const float*)d_in[4];
    float* out  = (float*)d_out;
    float* part = (float*)d_ws;

    if (ws_size >= WS_NEEDED) {
        hipLaunchKernelGGL(seesaw_main, dim3(MAIN_BLOCKS), dim3(MAIN_THREADS), 0, stream,
                           x, target, wm, part, out, 1);
        hipLaunchKernelGGL(seesaw_tail, dim3(NCLS + 1), dim3(MAIN_THREADS), 0, stream,
                           part, neg_in, pos_in, out);
    } else {
        hipLaunchKernelGGL(seesaw_init, dim3(1), dim3(256), 0, stream,
                           neg_in, pos_in, out);
        hipLaunchKernelGGL(seesaw_main, dim3(MAIN_BLOCKS), dim3(MAIN_THREADS), 0, stream,
                           x, target, wm, part, out, 0);
        hipLaunchKernelGGL(seesaw_fin, dim3(1), dim3(128), 0, stream, out);
    }
}